// Round 5
// baseline (1538.876 us; speedup 1.0000x reference)
//
#include <hip/hip_runtime.h>
#include <hip/hip_bf16.h>
#include <cstdint>

// Problem constants
#define B_   64
#define T_   2048
#define CIN  44
#define D_   512
#define DCC  640
#define REDD 160
#define BT   131072        // B_*T_
#define EPSV 1e-5f

typedef __attribute__((ext_vector_type(8))) short short8;
typedef __attribute__((ext_vector_type(4))) float f32x4;

#define MFMA16(a,b,c) __builtin_amdgcn_mfma_f32_16x16x32_bf16(a,b,c,0,0,0)

__device__ __forceinline__ float bf2f(unsigned short u) {
    union { unsigned int i; float f; } v; v.i = ((unsigned int)u) << 16; return v.f;
}
__device__ __forceinline__ unsigned short f2bf(float f) {
    union { float f; unsigned int i; } v; v.f = f;
    unsigned int r = v.i + 0x7FFFu + ((v.i >> 16) & 1u);   // RNE
    return (unsigned short)(r >> 16);
}

// ---------------------------------------------------------------- prep: weights -> bf16 FRAGMENT-PACKED
// Packed layout: for chunk c (64 cols), K-slab kb (32 k), tile t (16 cols):
//   packed[ ((c*(K/32) + kb)*4 + t)*512 + lane*8 + j ]  = W^T[n][k]
// with lane = quad*16+lid, n = c*64 + t*16 + lid, k = kb*32 + quad*8 + j.
__global__ void kprep(const float* __restrict__ hw1, const float* __restrict__ lw1, const float* __restrict__ ew1,
                      const float* __restrict__ hb1, const float* __restrict__ lb1, const float* __restrict__ eb1,
                      const float* __restrict__ hw2, const float* __restrict__ lw2, const float* __restrict__ ew2,
                      const float* __restrict__ hb2, const float* __restrict__ lb2, const float* __restrict__ eb2,
                      const float* __restrict__ gw,  const float* __restrict__ pw,  const float* __restrict__ ow,
                      unsigned short* __restrict__ w1T, float* __restrict__ b1,
                      unsigned short* __restrict__ w2T, float* __restrict__ b2,
                      unsigned short* __restrict__ gwT, unsigned short* __restrict__ pwT,
                      unsigned short* __restrict__ owT)
{
    int tid = blockIdx.x * blockDim.x + threadIdx.x;
    int nth = gridDim.x * blockDim.x;
    // gwT/pwT: N=640, K=640 -> chunk size 20*2048 = 40960
    for (int i = tid; i < 640 * 640; i += nth) {
        int c  = i / 40960, r = i - c * 40960;
        int kb = r / 2048;  int r2 = r - kb * 2048;
        int t  = r2 >> 9;   int l8 = r2 & 511;
        int lane = l8 >> 3, j = l8 & 7;
        int lid = lane & 15, quad = lane >> 4;
        int n = c * 64 + t * 16 + lid;
        int k = kb * 32 + quad * 8 + j;
        gwT[i] = f2bf(gw[(size_t)k * 640 + n]);
        pwT[i] = f2bf(pw[(size_t)k * 640 + n]);
    }
    // owT: N=512, K=640 (ow stride 512!)
    for (int i = tid; i < 512 * 640; i += nth) {
        int c  = i / 40960, r = i - c * 40960;
        int kb = r / 2048;  int r2 = r - kb * 2048;
        int t  = r2 >> 9;   int l8 = r2 & 511;
        int lane = l8 >> 3, j = l8 & 7;
        int lid = lane & 15, quad = lane >> 4;
        int n = c * 64 + t * 16 + lid;
        int k = kb * 32 + quad * 8 + j;
        owT[i] = f2bf(ow[(size_t)k * 512 + n]);
    }
    // w2T: N=640, K=256 local -> chunk size 8*2048 = 16384; block-diag groups
    for (int i = tid; i < 640 * 256; i += nth) {
        int c  = i / 16384, r = i - c * 16384;
        int kb = r / 2048;  int r2 = r - kb * 2048;
        int t  = r2 >> 9;   int l8 = r2 & 511;
        int lane = l8 >> 3, j = l8 & 7;
        int lid = lane & 15, quad = lane >> 4;
        int n = c * 64 + t * 16 + lid;
        int k = kb * 32 + quad * 8 + j;   // local k within group
        float v;
        if (n < 256)      v = hw2[k * 256 + n];
        else if (n < 512) v = lw2[k * 256 + (n - 256)];
        else              v = (k < 128) ? ew2[k * 128 + (n - 512)] : 0.0f;
        w2T[i] = f2bf(v);
    }
    // w1T: stage-1 weights, K padded to 32 per group (true K = 14/22/8).
    for (int i = tid; i < 640 * 32; i += nth) {
        int ct = i >> 9;  int l8 = i & 511;
        int lane = l8 >> 3, j = l8 & 7;
        int lid = lane & 15, quad = lane >> 4;
        int n = ct * 16 + lid;
        int k = quad * 8 + j;
        float v = 0.0f;
        if (n < 256)      { if (k < 14) v = hw1[k * 256 + n]; }
        else if (n < 512) { if (k < 22) v = lw1[k * 256 + (n - 256)]; }
        else              { if (k < 8)  v = ew1[k * 128 + (n - 512)]; }
        w1T[i] = f2bf(v);
    }
    for (int i = tid; i < 640; i += nth) {
        b1[i] = (i < 256) ? hb1[i] : ((i < 512) ? lb1[i - 256] : eb1[i - 512]);
        b2[i] = (i < 256) ? hb2[i] : ((i < 512) ? lb2[i - 256] : eb2[i - 512]);
    }
}

// ---------------------------------------------------------------- fused stage 1+2 (8 waves, M=64)
#define ZSTEP(KB, CUR, NXT) { \
    const int kk = (KB) * 32; \
    short8 ah0 = *(const short8*)&su[(0*16 + lid) * 648 + kk + quad * 8]; \
    short8 ah1 = *(const short8*)&su[(1*16 + lid) * 648 + kk + quad * 8]; \
    short8 ah2 = *(const short8*)&su[(2*16 + lid) * 648 + kk + quad * 8]; \
    short8 ah3 = *(const short8*)&su[(3*16 + lid) * 648 + kk + quad * 8]; \
    short8 al0 = *(const short8*)&su[(0*16 + lid) * 648 + 256 + kk + quad * 8]; \
    short8 al1 = *(const short8*)&su[(1*16 + lid) * 648 + 256 + kk + quad * 8]; \
    short8 al2 = *(const short8*)&su[(2*16 + lid) * 648 + 256 + kk + quad * 8]; \
    short8 al3 = *(const short8*)&su[(3*16 + lid) * 648 + 256 + kk + quad * 8]; \
    if ((KB) + 1 < 8) { \
        NXT[0] = *(const short8*)(w2T + off[0] + ((KB) + 1) * 2048); \
        NXT[1] = *(const short8*)(w2T + off[1] + ((KB) + 1) * 2048); \
        NXT[2] = *(const short8*)(w2T + off[2] + ((KB) + 1) * 2048); \
        NXT[3] = *(const short8*)(w2T + off[3] + ((KB) + 1) * 2048); \
        if ((KB) + 1 < 4) NXT[4] = *(const short8*)(w2T + off[4] + ((KB) + 1) * 2048); \
    } \
    acc[0][0] = MFMA16(ah0, CUR[0], acc[0][0]); acc[0][1] = MFMA16(ah1, CUR[0], acc[0][1]); \
    acc[0][2] = MFMA16(ah2, CUR[0], acc[0][2]); acc[0][3] = MFMA16(ah3, CUR[0], acc[0][3]); \
    acc[1][0] = MFMA16(ah0, CUR[1], acc[1][0]); acc[1][1] = MFMA16(ah1, CUR[1], acc[1][1]); \
    acc[1][2] = MFMA16(ah2, CUR[1], acc[1][2]); acc[1][3] = MFMA16(ah3, CUR[1], acc[1][3]); \
    acc[2][0] = MFMA16(al0, CUR[2], acc[2][0]); acc[2][1] = MFMA16(al1, CUR[2], acc[2][1]); \
    acc[2][2] = MFMA16(al2, CUR[2], acc[2][2]); acc[2][3] = MFMA16(al3, CUR[2], acc[2][3]); \
    acc[3][0] = MFMA16(al0, CUR[3], acc[3][0]); acc[3][1] = MFMA16(al1, CUR[3], acc[3][1]); \
    acc[3][2] = MFMA16(al2, CUR[3], acc[3][2]); acc[3][3] = MFMA16(al3, CUR[3], acc[3][3]); \
    if ((KB) < 4) { \
        short8 ae0 = *(const short8*)&su[(0*16 + lid) * 648 + 512 + kk + quad * 8]; \
        short8 ae1 = *(const short8*)&su[(1*16 + lid) * 648 + 512 + kk + quad * 8]; \
        short8 ae2 = *(const short8*)&su[(2*16 + lid) * 648 + 512 + kk + quad * 8]; \
        short8 ae3 = *(const short8*)&su[(3*16 + lid) * 648 + 512 + kk + quad * 8]; \
        acc[4][0] = MFMA16(ae0, CUR[4], acc[4][0]); acc[4][1] = MFMA16(ae1, CUR[4], acc[4][1]); \
        acc[4][2] = MFMA16(ae2, CUR[4], acc[4][2]); acc[4][3] = MFMA16(ae3, CUR[4], acc[4][3]); \
    } }

__global__ __launch_bounds__(512) void k_z(const float* __restrict__ x,
                                           const unsigned short* __restrict__ w1T,
                                           const float* __restrict__ b1,
                                           const unsigned short* __restrict__ w2T,
                                           const float* __restrict__ b2,
                                           unsigned short* __restrict__ z,
                                           float* __restrict__ y_sum)
{
    __shared__ __align__(16) unsigned short sx[64 * 96];
    __shared__ __align__(16) unsigned short su[64 * 648];
    int m0 = blockIdx.x * 64;
    int bidx = m0 >> 11;
    const float* xsrc = x + (size_t)m0 * CIN;
    for (int i = threadIdx.x; i < 64 * 96; i += 512) {
        int r = i / 96, c = i - r * 96;
        int slab = c >> 5, kc = c & 31;
        float v = 0.0f;
        if (slab == 0)      { if (kc < 14) v = xsrc[r * CIN + kc]; }
        else if (slab == 1) { if (kc < 22) v = xsrc[r * CIN + 14 + kc]; }
        else                { if (kc < 8)  v = xsrc[r * CIN + 36 + kc]; }
        sx[i] = f2bf(v);
    }
    __syncthreads();
    int wave = threadIdx.x >> 6, lane = threadIdx.x & 63, lid = lane & 15, quad = lane >> 4;
    const f32x4 z4 = {0.f, 0.f, 0.f, 0.f};
    // ---- stage 1: one K=32 MFMA per 16-col tile per 16-row band, silu -> su
    #pragma unroll
    for (int i = 0; i < 5; i++) {
        int ct = wave + 8 * i;
        int slab = ct >> 4;
        short8 bfr = *(const short8*)(w1T + (size_t)ct * 512 + lane * 8);
        int col = ct * 16 + lid;
        float bias = b1[col];
        #pragma unroll
        for (int rf = 0; rf < 4; rf++) {
            short8 a = *(const short8*)&sx[(rf * 16 + lid) * 96 + slab * 32 + quad * 8];
            f32x4 u = MFMA16(a, bfr, z4);
            #pragma unroll
            for (int r = 0; r < 4; r++) {
                float v0 = u[r] + bias;
                su[(rf * 16 + quad * 4 + r) * 648 + col] = f2bf(v0 / (1.0f + __expf(-v0)));
            }
        }
    }
    __syncthreads();
    // ---- stage 2
    int off[5];
    #pragma unroll
    for (int i = 0; i < 5; i++) {
        int ct = wave + 8 * i;
        off[i] = ((ct >> 2) * 32 + (ct & 3)) * 512 + lane * 8;
    }
    f32x4 acc[5][4];
    #pragma unroll
    for (int i = 0; i < 5; i++) { acc[i][0] = z4; acc[i][1] = z4; acc[i][2] = z4; acc[i][3] = z4; }
    short8 bA[5], bB[5];
    #pragma unroll
    for (int i = 0; i < 5; i++) bA[i] = *(const short8*)(w2T + off[i]);
    ZSTEP(0, bA, bB) ZSTEP(1, bB, bA) ZSTEP(2, bA, bB) ZSTEP(3, bB, bA)
    ZSTEP(4, bA, bB) ZSTEP(5, bB, bA) ZSTEP(6, bA, bB) ZSTEP(7, bB, bA)
    #pragma unroll
    for (int i = 0; i < 5; i++) {
        int ct = wave + 8 * i;
        int col = ct * 16 + lid;
        float bias = b2[col];
        float colsum = 0.0f;
        #pragma unroll
        for (int rf = 0; rf < 4; rf++) {
            #pragma unroll
            for (int r = 0; r < 4; r++) {
                float zv = acc[i][rf][r] + bias;
                z[(size_t)(m0 + rf * 16 + quad * 4 + r) * 640 + col] = f2bf(zv);
                colsum += zv;
            }
        }
        colsum += __shfl_xor(colsum, 16);
        colsum += __shfl_xor(colsum, 32);
        if (quad == 0) atomicAdd(&y_sum[bidx * 640 + col], colsum);
    }
}

// ---------------------------------------------------------------- SE MLP per batch
__global__ void k_se(const float* __restrict__ y_sum, const float* __restrict__ se_w1,
                     const float* __restrict__ se_w2, float* __restrict__ se)
{
    __shared__ float ya[640];
    __shared__ float rr[160];
    int b = blockIdx.x;
    for (int i = threadIdx.x; i < 640; i += 256) ya[i] = y_sum[b * 640 + i] * (1.0f / 2048.0f);
    __syncthreads();
    for (int o = threadIdx.x; o < 160; o += 256) {
        float a = 0.f;
        for (int k = 0; k < 640; k++) a += ya[k] * se_w1[k * 160 + o];
        rr[o] = fmaxf(a, 0.f);
    }
    __syncthreads();
    for (int c = threadIdx.x; c < 640; c += 256) {
        float a = 0.f;
        for (int o = 0; o < 160; o++) a += rr[o] * se_w2[o * 640 + c];
        se[b * 640 + c] = 1.0f / (1.0f + __expf(-a));
    }
}

// ---------------------------------------------------------------- FUSED GLU + LN + out-proj + GN stats
// Register-pressure discipline: peak live must stay <= 256 VGPR+AGPR (2 waves/SIMD).
// So the dual GEMM is split into TWO K-passes (g first -> sigmoid in place, then p),
// sharing one ping-pong buffer pair. Round-4's single-pass version peaked ~296 regs
// and spilled ~740 MB to scratch (WRITE_SIZE 1.0 GB vs 270 MB semantic).
#define GLUSTEP(KB, WT, CUR, NXT, ACC) { \
    const int kk = (KB) * 32; \
    short8 a0 = *(const short8*)&sz[(0*16 + lid) * 648 + kk + quad * 8]; \
    short8 a1 = *(const short8*)&sz[(1*16 + lid) * 648 + kk + quad * 8]; \
    short8 a2 = *(const short8*)&sz[(2*16 + lid) * 648 + kk + quad * 8]; \
    short8 a3 = *(const short8*)&sz[(3*16 + lid) * 648 + kk + quad * 8]; \
    if ((KB) < 19) { \
        _Pragma("unroll") \
        for (int i = 0; i < 5; i++) \
            NXT[i] = *(const short8*)(WT + offG[i] + ((KB) + 1) * 2048); \
    } \
    _Pragma("unroll") \
    for (int i = 0; i < 5; i++) { \
        ACC[i][0] = MFMA16(a0, CUR[i], ACC[i][0]); \
        ACC[i][1] = MFMA16(a1, CUR[i], ACC[i][1]); \
        ACC[i][2] = MFMA16(a2, CUR[i], ACC[i][2]); \
        ACC[i][3] = MFMA16(a3, CUR[i], ACC[i][3]); \
    } }

#define OSTEP(KB, CUR, NXT) { \
    const int kk = (KB) * 32; \
    short8 a0 = *(const short8*)&sz[(0 * 16 + lid) * 648 + kk + quad * 8]; \
    short8 a1 = *(const short8*)&sz[(1 * 16 + lid) * 648 + kk + quad * 8]; \
    short8 a2 = *(const short8*)&sz[(2 * 16 + lid) * 648 + kk + quad * 8]; \
    short8 a3 = *(const short8*)&sz[(3 * 16 + lid) * 648 + kk + quad * 8]; \
    if ((KB) < 19) { \
        _Pragma("unroll") \
        for (int i = 0; i < 4; i++) \
            NXT[i] = *(const short8*)(owT + offO[i] + ((KB) + 1) * 2048); \
    } \
    acc[0][0] = MFMA16(a0, CUR[0], acc[0][0]); acc[0][1] = MFMA16(a1, CUR[0], acc[0][1]); \
    acc[0][2] = MFMA16(a2, CUR[0], acc[0][2]); acc[0][3] = MFMA16(a3, CUR[0], acc[0][3]); \
    acc[1][0] = MFMA16(a0, CUR[1], acc[1][0]); acc[1][1] = MFMA16(a1, CUR[1], acc[1][1]); \
    acc[1][2] = MFMA16(a2, CUR[1], acc[1][2]); acc[1][3] = MFMA16(a3, CUR[1], acc[1][3]); \
    acc[2][0] = MFMA16(a0, CUR[2], acc[2][0]); acc[2][1] = MFMA16(a1, CUR[2], acc[2][1]); \
    acc[2][2] = MFMA16(a2, CUR[2], acc[2][2]); acc[2][3] = MFMA16(a3, CUR[2], acc[2][3]); \
    acc[3][0] = MFMA16(a0, CUR[3], acc[3][0]); acc[3][1] = MFMA16(a1, CUR[3], acc[3][1]); \
    acc[3][2] = MFMA16(a2, CUR[3], acc[3][2]); acc[3][3] = MFMA16(a3, CUR[3], acc[3][3]); }

__global__ __launch_bounds__(512) void k_gluout(const unsigned short* __restrict__ z,
                                                const float* __restrict__ se,
                                                const unsigned short* __restrict__ gwT,
                                                const unsigned short* __restrict__ pwT,
                                                const float* __restrict__ gb, const float* __restrict__ pb,
                                                const float* __restrict__ ln_w, const float* __restrict__ ln_b,
                                                const unsigned short* __restrict__ owT,
                                                const float* __restrict__ ob,
                                                float* __restrict__ outp, float* __restrict__ gnstats)
{
    __shared__ __align__(16) unsigned short sz[64 * 648];
    __shared__ float spart[64][8];
    __shared__ float sqart[64][8];
    __shared__ float sA[64], sB[64];
    int m0 = blockIdx.x * 64;
    int bidx = m0 >> 11;
    const unsigned short* zsrc = z + (size_t)m0 * 640;
    const float* seb = se + bidx * 640;
    for (int i = threadIdx.x; i < 5120; i += 512) {        // stage z_se = bf16(z * se)
        int e = i * 8, r = e / 640, c = e - r * 640;
        short8 v = *(const short8*)(zsrc + e);
        unsigned short o8[8];
        #pragma unroll
        for (int j = 0; j < 8; j++) {
            float f = bf2f(((const unsigned short*)&v)[j]) * seb[c + j];
            o8[j] = f2bf(f);
        }
        *(short8*)&sz[r * 648 + c] = *(short8*)o8;
    }
    __syncthreads();
    int wave = threadIdx.x >> 6, lane = threadIdx.x & 63, lid = lane & 15, quad = lane >> 4;
    const f32x4 z4 = {0.f, 0.f, 0.f, 0.f};
    int offG[5];
    #pragma unroll
    for (int i = 0; i < 5; i++) {
        int ct = wave + 8 * i;
        offG[i] = ((ct >> 2) * 80 + (ct & 3)) * 512 + lane * 8;
    }
    // ---- g-pass
    f32x4 ag[5][4];
    #pragma unroll
    for (int i = 0; i < 5; i++) { ag[i][0] = z4; ag[i][1] = z4; ag[i][2] = z4; ag[i][3] = z4; }
    short8 wbA[5], wbB[5];
    #pragma unroll
    for (int i = 0; i < 5; i++) wbA[i] = *(const short8*)(gwT + offG[i]);
    for (int kb = 0; kb < 20; kb += 2) {
        GLUSTEP(kb,     gwT, wbA, wbB, ag)
        GLUSTEP(kb + 1, gwT, wbB, wbA, ag)
    }
    // sigmoid(g + gb) in place (f32 -> no numeric change vs fused version)
    #pragma unroll
    for (int i = 0; i < 5; i++) {
        int col = (wave + 8 * i) * 16 + lid;
        float gbv = gb[col];
        #pragma unroll
        for (int rf = 0; rf < 4; rf++)
            #pragma unroll
            for (int r = 0; r < 4; r++)
                ag[i][rf][r] = 1.0f / (1.0f + __expf(-(ag[i][rf][r] + gbv)));
    }
    // ---- p-pass (reuses the same ping-pong buffers)
    f32x4 ap[5][4];
    #pragma unroll
    for (int i = 0; i < 5; i++) { ap[i][0] = z4; ap[i][1] = z4; ap[i][2] = z4; ap[i][3] = z4; }
    #pragma unroll
    for (int i = 0; i < 5; i++) wbA[i] = *(const short8*)(pwT + offG[i]);
    for (int kb = 0; kb < 20; kb += 2) {
        GLUSTEP(kb,     pwT, wbA, wbB, ap)
        GLUSTEP(kb + 1, pwT, wbB, wbA, ap)
    }
    // ---- h = sg*(p+pb) + (1-sg)*z_se  (into ag), block-local LN partial stats
    float hs[4][4] = {{0,0,0,0},{0,0,0,0},{0,0,0,0},{0,0,0,0}};
    float hq[4][4] = {{0,0,0,0},{0,0,0,0},{0,0,0,0},{0,0,0,0}};
    #pragma unroll
    for (int i = 0; i < 5; i++) {
        int ct = wave + 8 * i;
        int col = ct * 16 + lid;
        float pbv = pb[col];
        #pragma unroll
        for (int rf = 0; rf < 4; rf++) {
            #pragma unroll
            for (int r = 0; r < 4; r++) {
                int row = rf * 16 + quad * 4 + r;
                float sg = ag[i][rf][r];
                float pl = ap[i][rf][r] + pbv;
                float zv = bf2f(sz[row * 648 + col]);
                float hv = sg * pl + (1.0f - sg) * zv;
                ag[i][rf][r] = hv;                       // keep h in regs
                hs[rf][r] += hv; hq[rf][r] += hv * hv;
            }
        }
    }
    #pragma unroll
    for (int s = 1; s < 16; s <<= 1) {
        #pragma unroll
        for (int rf = 0; rf < 4; rf++)
            #pragma unroll
            for (int r = 0; r < 4; r++) {
                hs[rf][r] += __shfl_xor(hs[rf][r], s);
                hq[rf][r] += __shfl_xor(hq[rf][r], s);
            }
    }
    if (lid == 0) {
        #pragma unroll
        for (int rf = 0; rf < 4; rf++)
            #pragma unroll
            for (int r = 0; r < 4; r++) {
                int row = rf * 16 + quad * 4 + r;
                spart[row][wave] = hs[rf][r];
                sqart[row][wave] = hq[rf][r];
            }
    }
    __syncthreads();                                     // (A) all z reads + partials done
    if (threadIdx.x < 64) {
        float s1 = 0.f, s2 = 0.f;
        #pragma unroll
        for (int w = 0; w < 8; w++) { s1 += spart[threadIdx.x][w]; s2 += sqart[threadIdx.x][w]; }
        float mu = s1 * (1.0f / 640.0f);
        float var = s2 * (1.0f / 640.0f) - mu * mu;
        float rs = rsqrtf(var + EPSV);
        sA[threadIdx.x] = rs;
        sB[threadIdx.x] = -mu * rs;
    }
    __syncthreads();                                     // (B) stats ready
    // ---- write LN(h) in place over z_se
    #pragma unroll
    for (int i = 0; i < 5; i++) {
        int ct = wave + 8 * i;
        int col = ct * 16 + lid;
        float lw = ln_w[col], lb = ln_b[col];
        #pragma unroll
        for (int rf = 0; rf < 4; rf++) {
            #pragma unroll
            for (int r = 0; r < 4; r++) {
                int row = rf * 16 + quad * 4 + r;
                float f = ag[i][rf][r] * sA[row] + sB[row];
                sz[row * 648 + col] = f2bf(f * lw + lb);
            }
        }
    }
    __syncthreads();                                     // (C) h_ln staged
    // ---- out-proj GEMM
    int offO[4];
    #pragma unroll
    for (int i = 0; i < 4; i++) {
        int ct = wave + 8 * i;
        offO[i] = ((ct >> 2) * 80 + (ct & 3)) * 512 + lane * 8;
    }
    f32x4 acc[4][4];
    #pragma unroll
    for (int i = 0; i < 4; i++) { acc[i][0] = z4; acc[i][1] = z4; acc[i][2] = z4; acc[i][3] = z4; }
    short8 bA[4], bB[4];
    #pragma unroll
    for (int i = 0; i < 4; i++) bA[i] = *(const short8*)(owT + offO[i]);
    for (int kb = 0; kb < 20; kb += 2) {
        OSTEP(kb, bA, bB)
        OSTEP(kb + 1, bB, bA)
    }
    #pragma unroll
    for (int i = 0; i < 4; i++) {
        int ct = wave + 8 * i;
        int col = ct * 16 + lid;
        float obv = ob[col];
        float gs = 0.f, gq = 0.f;
        #pragma unroll
        for (int rf = 0; rf < 4; rf++) {
            #pragma unroll
            for (int r = 0; r < 4; r++) {
                int row = rf * 16 + quad * 4 + r;
                float v = acc[i][rf][r] + obv;
                outp[(size_t)(m0 + row) * 512 + col] = v;
                gs += v; gq += v * v;
            }
        }
        #pragma unroll
        for (int s = 1; s < 64; s <<= 1) { gs += __shfl_xor(gs, s); gq += __shfl_xor(gq, s); }
        if (lane == 0) {
            int grp = ct >> 2;
            atomicAdd(&gnstats[(bidx * 8 + grp) * 2 + 0], gs);
            atomicAdd(&gnstats[(bidx * 8 + grp) * 2 + 1], gq);
        }
    }
}

// ---------------------------------------------------------------- GroupNorm finalize (in-place on d_out)
__global__ void k_gn(float* __restrict__ outp, const float* __restrict__ gnstats,
                     const float* __restrict__ gn_w, const float* __restrict__ gn_b)
{
    int idx = blockIdx.x * 256 + threadIdx.x;
    size_t e = (size_t)idx * 4;
    int c = (int)(e & 511);
    size_t row = e >> 9;
    int b = (int)(row >> 11);
    int grp = c >> 6;
    float s1 = gnstats[(b * 8 + grp) * 2 + 0];
    float s2 = gnstats[(b * 8 + grp) * 2 + 1];
    const float inv = 1.0f / 131072.0f;
    float mu = s1 * inv;
    float var = s2 * inv - mu * mu;
    float rs = rsqrtf(var + EPSV);
    float4 v = *(const float4*)(outp + e);
    float4 w = *(const float4*)(gn_w + c);
    float4 bb = *(const float4*)(gn_b + c);
    float4 o;
    o.x = (v.x - mu) * rs * w.x + bb.x;
    o.y = (v.y - mu) * rs * w.y + bb.y;
    o.z = (v.z - mu) * rs * w.z + bb.z;
    o.w = (v.w - mu) * rs * w.w + bb.w;
    *(float4*)(outp + e) = o;
}

// ----------------------------------------------------------------
extern "C" void kernel_launch(void* const* d_in, const int* in_sizes, int n_in,
                              void* d_out, int out_size, void* d_ws, size_t ws_size,
                              hipStream_t stream)
{
    const float* x     = (const float*)d_in[0];
    const float* hw1   = (const float*)d_in[1];
    const float* hb1   = (const float*)d_in[2];
    const float* hw2   = (const float*)d_in[3];
    const float* hb2   = (const float*)d_in[4];
    const float* lw1   = (const float*)d_in[5];
    const float* lb1   = (const float*)d_in[6];
    const float* lw2   = (const float*)d_in[7];
    const float* lb2   = (const float*)d_in[8];
    const float* ew1   = (const float*)d_in[9];
    const float* eb1   = (const float*)d_in[10];
    const float* ew2   = (const float*)d_in[11];
    const float* eb2   = (const float*)d_in[12];
    const float* se_w1 = (const float*)d_in[13];
    const float* se_w2 = (const float*)d_in[14];
    const float* gw    = (const float*)d_in[15];
    const float* gb    = (const float*)d_in[16];
    const float* pw    = (const float*)d_in[17];
    const float* pb    = (const float*)d_in[18];
    const float* ln_w  = (const float*)d_in[19];
    const float* ln_b  = (const float*)d_in[20];
    const float* ow    = (const float*)d_in[21];
    const float* ob    = (const float*)d_in[22];
    const float* gn_w  = (const float*)d_in[23];
    const float* gn_b  = (const float*)d_in[24];

    char* ws = (char*)d_ws;
    size_t off = 0;
    unsigned short* w2T  = (unsigned short*)(ws + off); off += (size_t)640 * 256 * 2;
    float*          b2   = (float*)(ws + off);          off += 640 * 4;
    unsigned short* gwT  = (unsigned short*)(ws + off); off += (size_t)640 * 640 * 2;
    unsigned short* pwT  = (unsigned short*)(ws + off); off += (size_t)640 * 640 * 2;
    unsigned short* owT  = (unsigned short*)(ws + off); off += (size_t)512 * 640 * 2;
    unsigned short* w1T  = (unsigned short*)(ws + off); off += (size_t)640 * 32 * 2;
    float*          b1   = (float*)(ws + off);          off += 640 * 4;
    float*          ysum = (float*)(ws + off);          off += (size_t)64 * 640 * 4;
    float*          sebuf= (float*)(ws + off);          off += (size_t)64 * 640 * 4;
    float*          gnst = (float*)(ws + off);          off += (size_t)64 * 8 * 2 * 4;
    unsigned short* zbuf = (unsigned short*)(ws + off); off += (size_t)BT * 640 * 2;

    float* outp = (float*)d_out;

    hipMemsetAsync(ysum, 0, (size_t)64 * 640 * 4, stream);
    hipMemsetAsync(gnst, 0, (size_t)64 * 8 * 2 * 4, stream);

    kprep<<<512, 256, 0, stream>>>(hw1, lw1, ew1, hb1, lb1, eb1,
                                   hw2, lw2, ew2, hb2, lb2, eb2,
                                   gw, pw, ow, w1T, b1, w2T, b2, gwT, pwT, owT);
    k_z<<<BT / 64, 512, 0, stream>>>(x, w1T, b1, w2T, b2, zbuf, ysum);
    k_se<<<64, 256, 0, stream>>>(ysum, se_w1, se_w2, sebuf);
    k_gluout<<<BT / 64, 512, 0, stream>>>(zbuf, sebuf, gwT, pwT, gb, pb,
                                          ln_w, ln_b, owT, ob, outp, gnst);
    k_gn<<<(BT * 512) / (256 * 4), 256, 0, stream>>>(outp, gnst, gn_w, gn_b);
}

// Round 6
// 1501.976 us; speedup vs baseline: 1.0246x; 1.0246x over previous
//
#include <hip/hip_runtime.h>
#include <hip/hip_bf16.h>
#include <cstdint>

// Problem constants
#define B_   64
#define T_   2048
#define CIN  44
#define D_   512
#define DCC  640
#define REDD 160
#define BT   131072        // B_*T_
#define EPSV 1e-5f

typedef __attribute__((ext_vector_type(8))) short short8;
typedef __attribute__((ext_vector_type(4))) float f32x4;

#define MFMA16(a,b,c) __builtin_amdgcn_mfma_f32_16x16x32_bf16(a,b,c,0,0,0)

__device__ __forceinline__ float bf2f(unsigned short u) {
    union { unsigned int i; float f; } v; v.i = ((unsigned int)u) << 16; return v.f;
}
__device__ __forceinline__ unsigned short f2bf(float f) {
    union { float f; unsigned int i; } v; v.f = f;
    unsigned int r = v.i + 0x7FFFu + ((v.i >> 16) & 1u);   // RNE
    return (unsigned short)(r >> 16);
}

// ---------------------------------------------------------------- prep: weights -> bf16 FRAGMENT-PACKED
// Packed layout: for chunk c (64 cols), K-slab kb (32 k), tile t (16 cols):
//   packed[ ((c*(K/32) + kb)*4 + t)*512 + lane*8 + j ]  = W^T[n][k]
// with lane = quad*16+lid, n = c*64 + t*16 + lid, k = kb*32 + quad*8 + j.
__global__ void kprep(const float* __restrict__ hw1, const float* __restrict__ lw1, const float* __restrict__ ew1,
                      const float* __restrict__ hb1, const float* __restrict__ lb1, const float* __restrict__ eb1,
                      const float* __restrict__ hw2, const float* __restrict__ lw2, const float* __restrict__ ew2,
                      const float* __restrict__ hb2, const float* __restrict__ lb2, const float* __restrict__ eb2,
                      const float* __restrict__ gw,  const float* __restrict__ pw,  const float* __restrict__ ow,
                      unsigned short* __restrict__ w1T, float* __restrict__ b1,
                      unsigned short* __restrict__ w2T, float* __restrict__ b2,
                      unsigned short* __restrict__ gwT, unsigned short* __restrict__ pwT,
                      unsigned short* __restrict__ owT)
{
    int tid = blockIdx.x * blockDim.x + threadIdx.x;
    int nth = gridDim.x * blockDim.x;
    // gwT/pwT: N=640, K=640 -> chunk size 20*2048 = 40960
    for (int i = tid; i < 640 * 640; i += nth) {
        int c  = i / 40960, r = i - c * 40960;
        int kb = r / 2048;  int r2 = r - kb * 2048;
        int t  = r2 >> 9;   int l8 = r2 & 511;
        int lane = l8 >> 3, j = l8 & 7;
        int lid = lane & 15, quad = lane >> 4;
        int n = c * 64 + t * 16 + lid;
        int k = kb * 32 + quad * 8 + j;
        gwT[i] = f2bf(gw[(size_t)k * 640 + n]);
        pwT[i] = f2bf(pw[(size_t)k * 640 + n]);
    }
    // owT: N=512, K=640 (ow stride 512!)
    for (int i = tid; i < 512 * 640; i += nth) {
        int c  = i / 40960, r = i - c * 40960;
        int kb = r / 2048;  int r2 = r - kb * 2048;
        int t  = r2 >> 9;   int l8 = r2 & 511;
        int lane = l8 >> 3, j = l8 & 7;
        int lid = lane & 15, quad = lane >> 4;
        int n = c * 64 + t * 16 + lid;
        int k = kb * 32 + quad * 8 + j;
        owT[i] = f2bf(ow[(size_t)k * 512 + n]);
    }
    // w2T: N=640, K=256 local -> chunk size 8*2048 = 16384; block-diag groups
    for (int i = tid; i < 640 * 256; i += nth) {
        int c  = i / 16384, r = i - c * 16384;
        int kb = r / 2048;  int r2 = r - kb * 2048;
        int t  = r2 >> 9;   int l8 = r2 & 511;
        int lane = l8 >> 3, j = l8 & 7;
        int lid = lane & 15, quad = lane >> 4;
        int n = c * 64 + t * 16 + lid;
        int k = kb * 32 + quad * 8 + j;   // local k within group
        float v;
        if (n < 256)      v = hw2[k * 256 + n];
        else if (n < 512) v = lw2[k * 256 + (n - 256)];
        else              v = (k < 128) ? ew2[k * 128 + (n - 512)] : 0.0f;
        w2T[i] = f2bf(v);
    }
    // w1T: stage-1 weights, K padded to 32 per group (true K = 14/22/8).
    for (int i = tid; i < 640 * 32; i += nth) {
        int ct = i >> 9;  int l8 = i & 511;
        int lane = l8 >> 3, j = l8 & 7;
        int lid = lane & 15, quad = lane >> 4;
        int n = ct * 16 + lid;
        int k = quad * 8 + j;
        float v = 0.0f;
        if (n < 256)      { if (k < 14) v = hw1[k * 256 + n]; }
        else if (n < 512) { if (k < 22) v = lw1[k * 256 + (n - 256)]; }
        else              { if (k < 8)  v = ew1[k * 128 + (n - 512)]; }
        w1T[i] = f2bf(v);
    }
    for (int i = tid; i < 640; i += nth) {
        b1[i] = (i < 256) ? hb1[i] : ((i < 512) ? lb1[i - 256] : eb1[i - 512]);
        b2[i] = (i < 256) ? hb2[i] : ((i < 512) ? lb2[i - 256] : eb2[i - 512]);
    }
}

// ---------------------------------------------------------------- fused stage 1+2 (8 waves, M=64)
// __launch_bounds__(512, 2): LDS (84 KB) already limits to 1 block/CU = 2 waves/SIMD,
// so grant the allocator the full 256-reg budget (default heuristic caps at 128 and
// spills the ~170-reg live set of stage 2).
#define ZSTEP(KB, CUR, NXT) { \
    const int kk = (KB) * 32; \
    short8 ah0 = *(const short8*)&su[(0*16 + lid) * 648 + kk + quad * 8]; \
    short8 ah1 = *(const short8*)&su[(1*16 + lid) * 648 + kk + quad * 8]; \
    short8 ah2 = *(const short8*)&su[(2*16 + lid) * 648 + kk + quad * 8]; \
    short8 ah3 = *(const short8*)&su[(3*16 + lid) * 648 + kk + quad * 8]; \
    short8 al0 = *(const short8*)&su[(0*16 + lid) * 648 + 256 + kk + quad * 8]; \
    short8 al1 = *(const short8*)&su[(1*16 + lid) * 648 + 256 + kk + quad * 8]; \
    short8 al2 = *(const short8*)&su[(2*16 + lid) * 648 + 256 + kk + quad * 8]; \
    short8 al3 = *(const short8*)&su[(3*16 + lid) * 648 + 256 + kk + quad * 8]; \
    if ((KB) + 1 < 8) { \
        NXT[0] = *(const short8*)(w2T + off[0] + ((KB) + 1) * 2048); \
        NXT[1] = *(const short8*)(w2T + off[1] + ((KB) + 1) * 2048); \
        NXT[2] = *(const short8*)(w2T + off[2] + ((KB) + 1) * 2048); \
        NXT[3] = *(const short8*)(w2T + off[3] + ((KB) + 1) * 2048); \
        if ((KB) + 1 < 4) NXT[4] = *(const short8*)(w2T + off[4] + ((KB) + 1) * 2048); \
    } \
    acc[0][0] = MFMA16(ah0, CUR[0], acc[0][0]); acc[0][1] = MFMA16(ah1, CUR[0], acc[0][1]); \
    acc[0][2] = MFMA16(ah2, CUR[0], acc[0][2]); acc[0][3] = MFMA16(ah3, CUR[0], acc[0][3]); \
    acc[1][0] = MFMA16(ah0, CUR[1], acc[1][0]); acc[1][1] = MFMA16(ah1, CUR[1], acc[1][1]); \
    acc[1][2] = MFMA16(ah2, CUR[1], acc[1][2]); acc[1][3] = MFMA16(ah3, CUR[1], acc[1][3]); \
    acc[2][0] = MFMA16(al0, CUR[2], acc[2][0]); acc[2][1] = MFMA16(al1, CUR[2], acc[2][1]); \
    acc[2][2] = MFMA16(al2, CUR[2], acc[2][2]); acc[2][3] = MFMA16(al3, CUR[2], acc[2][3]); \
    acc[3][0] = MFMA16(al0, CUR[3], acc[3][0]); acc[3][1] = MFMA16(al1, CUR[3], acc[3][1]); \
    acc[3][2] = MFMA16(al2, CUR[3], acc[3][2]); acc[3][3] = MFMA16(al3, CUR[3], acc[3][3]); \
    if ((KB) < 4) { \
        short8 ae0 = *(const short8*)&su[(0*16 + lid) * 648 + 512 + kk + quad * 8]; \
        short8 ae1 = *(const short8*)&su[(1*16 + lid) * 648 + 512 + kk + quad * 8]; \
        short8 ae2 = *(const short8*)&su[(2*16 + lid) * 648 + 512 + kk + quad * 8]; \
        short8 ae3 = *(const short8*)&su[(3*16 + lid) * 648 + 512 + kk + quad * 8]; \
        acc[4][0] = MFMA16(ae0, CUR[4], acc[4][0]); acc[4][1] = MFMA16(ae1, CUR[4], acc[4][1]); \
        acc[4][2] = MFMA16(ae2, CUR[4], acc[4][2]); acc[4][3] = MFMA16(ae3, CUR[4], acc[4][3]); \
    } }

__global__ __launch_bounds__(512, 2) void k_z(const float* __restrict__ x,
                                              const unsigned short* __restrict__ w1T,
                                              const float* __restrict__ b1,
                                              const unsigned short* __restrict__ w2T,
                                              const float* __restrict__ b2,
                                              unsigned short* __restrict__ z,
                                              float* __restrict__ y_sum)
{
    __shared__ __align__(16) unsigned short sx[64 * 96];
    __shared__ __align__(16) unsigned short su[64 * 648];
    int m0 = blockIdx.x * 64;
    int bidx = m0 >> 11;
    const float* xsrc = x + (size_t)m0 * CIN;
    for (int i = threadIdx.x; i < 64 * 96; i += 512) {
        int r = i / 96, c = i - r * 96;
        int slab = c >> 5, kc = c & 31;
        float v = 0.0f;
        if (slab == 0)      { if (kc < 14) v = xsrc[r * CIN + kc]; }
        else if (slab == 1) { if (kc < 22) v = xsrc[r * CIN + 14 + kc]; }
        else                { if (kc < 8)  v = xsrc[r * CIN + 36 + kc]; }
        sx[i] = f2bf(v);
    }
    __syncthreads();
    int wave = threadIdx.x >> 6, lane = threadIdx.x & 63, lid = lane & 15, quad = lane >> 4;
    const f32x4 z4 = {0.f, 0.f, 0.f, 0.f};
    // ---- stage 1: one K=32 MFMA per 16-col tile per 16-row band, silu -> su
    #pragma unroll
    for (int i = 0; i < 5; i++) {
        int ct = wave + 8 * i;
        int slab = ct >> 4;
        short8 bfr = *(const short8*)(w1T + (size_t)ct * 512 + lane * 8);
        int col = ct * 16 + lid;
        float bias = b1[col];
        #pragma unroll
        for (int rf = 0; rf < 4; rf++) {
            short8 a = *(const short8*)&sx[(rf * 16 + lid) * 96 + slab * 32 + quad * 8];
            f32x4 u = MFMA16(a, bfr, z4);
            #pragma unroll
            for (int r = 0; r < 4; r++) {
                float v0 = u[r] + bias;
                su[(rf * 16 + quad * 4 + r) * 648 + col] = f2bf(v0 / (1.0f + __expf(-v0)));
            }
        }
    }
    __syncthreads();
    // ---- stage 2
    int off[5];
    #pragma unroll
    for (int i = 0; i < 5; i++) {
        int ct = wave + 8 * i;
        off[i] = ((ct >> 2) * 32 + (ct & 3)) * 512 + lane * 8;
    }
    f32x4 acc[5][4];
    #pragma unroll
    for (int i = 0; i < 5; i++) { acc[i][0] = z4; acc[i][1] = z4; acc[i][2] = z4; acc[i][3] = z4; }
    short8 bA[5], bB[5];
    #pragma unroll
    for (int i = 0; i < 5; i++) bA[i] = *(const short8*)(w2T + off[i]);
    ZSTEP(0, bA, bB) ZSTEP(1, bB, bA) ZSTEP(2, bA, bB) ZSTEP(3, bB, bA)
    ZSTEP(4, bA, bB) ZSTEP(5, bB, bA) ZSTEP(6, bA, bB) ZSTEP(7, bB, bA)
    #pragma unroll
    for (int i = 0; i < 5; i++) {
        int ct = wave + 8 * i;
        int col = ct * 16 + lid;
        float bias = b2[col];
        float colsum = 0.0f;
        #pragma unroll
        for (int rf = 0; rf < 4; rf++) {
            #pragma unroll
            for (int r = 0; r < 4; r++) {
                float zv = acc[i][rf][r] + bias;
                z[(size_t)(m0 + rf * 16 + quad * 4 + r) * 640 + col] = f2bf(zv);
                colsum += zv;
            }
        }
        colsum += __shfl_xor(colsum, 16);
        colsum += __shfl_xor(colsum, 32);
        if (quad == 0) atomicAdd(&y_sum[bidx * 640 + col], colsum);
    }
}

// ---------------------------------------------------------------- SE MLP per batch
__global__ void k_se(const float* __restrict__ y_sum, const float* __restrict__ se_w1,
                     const float* __restrict__ se_w2, float* __restrict__ se)
{
    __shared__ float ya[640];
    __shared__ float rr[160];
    int b = blockIdx.x;
    for (int i = threadIdx.x; i < 640; i += 256) ya[i] = y_sum[b * 640 + i] * (1.0f / 2048.0f);
    __syncthreads();
    for (int o = threadIdx.x; o < 160; o += 256) {
        float a = 0.f;
        for (int k = 0; k < 640; k++) a += ya[k] * se_w1[k * 160 + o];
        rr[o] = fmaxf(a, 0.f);
    }
    __syncthreads();
    for (int c = threadIdx.x; c < 640; c += 256) {
        float a = 0.f;
        for (int o = 0; o < 160; o++) a += rr[o] * se_w2[o * 640 + c];
        se[b * 640 + c] = 1.0f / (1.0f + __expf(-a));
    }
}

// ---------------------------------------------------------------- FUSED GLU + LN + out-proj + GN stats
// Two K-passes (g then p) sharing one ping-pong buffer pair keeps peak live ~240 regs;
// __launch_bounds__(512, 2) grants the 256-reg budget (LDS already limits to 1 block/CU,
// so the compiler's default 128-reg / 2-block-per-CU target is pure spill with no
// occupancy gain -- rounds 4/5 showed 460-740 MB scratch traffic from that cap).
#define GLUSTEP(KB, WT, CUR, NXT, ACC) { \
    const int kk = (KB) * 32; \
    short8 a0 = *(const short8*)&sz[(0*16 + lid) * 648 + kk + quad * 8]; \
    short8 a1 = *(const short8*)&sz[(1*16 + lid) * 648 + kk + quad * 8]; \
    short8 a2 = *(const short8*)&sz[(2*16 + lid) * 648 + kk + quad * 8]; \
    short8 a3 = *(const short8*)&sz[(3*16 + lid) * 648 + kk + quad * 8]; \
    if ((KB) < 19) { \
        _Pragma("unroll") \
        for (int i = 0; i < 5; i++) \
            NXT[i] = *(const short8*)(WT + offG[i] + ((KB) + 1) * 2048); \
    } \
    _Pragma("unroll") \
    for (int i = 0; i < 5; i++) { \
        ACC[i][0] = MFMA16(a0, CUR[i], ACC[i][0]); \
        ACC[i][1] = MFMA16(a1, CUR[i], ACC[i][1]); \
        ACC[i][2] = MFMA16(a2, CUR[i], ACC[i][2]); \
        ACC[i][3] = MFMA16(a3, CUR[i], ACC[i][3]); \
    } }

#define OSTEP(KB, CUR, NXT) { \
    const int kk = (KB) * 32; \
    short8 a0 = *(const short8*)&sz[(0 * 16 + lid) * 648 + kk + quad * 8]; \
    short8 a1 = *(const short8*)&sz[(1 * 16 + lid) * 648 + kk + quad * 8]; \
    short8 a2 = *(const short8*)&sz[(2 * 16 + lid) * 648 + kk + quad * 8]; \
    short8 a3 = *(const short8*)&sz[(3 * 16 + lid) * 648 + kk + quad * 8]; \
    if ((KB) < 19) { \
        _Pragma("unroll") \
        for (int i = 0; i < 4; i++) \
            NXT[i] = *(const short8*)(owT + offO[i] + ((KB) + 1) * 2048); \
    } \
    acc[0][0] = MFMA16(a0, CUR[0], acc[0][0]); acc[0][1] = MFMA16(a1, CUR[0], acc[0][1]); \
    acc[0][2] = MFMA16(a2, CUR[0], acc[0][2]); acc[0][3] = MFMA16(a3, CUR[0], acc[0][3]); \
    acc[1][0] = MFMA16(a0, CUR[1], acc[1][0]); acc[1][1] = MFMA16(a1, CUR[1], acc[1][1]); \
    acc[1][2] = MFMA16(a2, CUR[1], acc[1][2]); acc[1][3] = MFMA16(a3, CUR[1], acc[1][3]); \
    acc[2][0] = MFMA16(a0, CUR[2], acc[2][0]); acc[2][1] = MFMA16(a1, CUR[2], acc[2][1]); \
    acc[2][2] = MFMA16(a2, CUR[2], acc[2][2]); acc[2][3] = MFMA16(a3, CUR[2], acc[2][3]); \
    acc[3][0] = MFMA16(a0, CUR[3], acc[3][0]); acc[3][1] = MFMA16(a1, CUR[3], acc[3][1]); \
    acc[3][2] = MFMA16(a2, CUR[3], acc[3][2]); acc[3][3] = MFMA16(a3, CUR[3], acc[3][3]); }

__global__ __launch_bounds__(512, 2) void k_gluout(const unsigned short* __restrict__ z,
                                                   const float* __restrict__ se,
                                                   const unsigned short* __restrict__ gwT,
                                                   const unsigned short* __restrict__ pwT,
                                                   const float* __restrict__ gb, const float* __restrict__ pb,
                                                   const float* __restrict__ ln_w, const float* __restrict__ ln_b,
                                                   const unsigned short* __restrict__ owT,
                                                   const float* __restrict__ ob,
                                                   float* __restrict__ outp, float* __restrict__ gnstats)
{
    __shared__ __align__(16) unsigned short sz[64 * 648];
    __shared__ float spart[64][8];
    __shared__ float sqart[64][8];
    __shared__ float sA[64], sB[64];
    int m0 = blockIdx.x * 64;
    int bidx = m0 >> 11;
    const unsigned short* zsrc = z + (size_t)m0 * 640;
    const float* seb = se + bidx * 640;
    for (int i = threadIdx.x; i < 5120; i += 512) {        // stage z_se = bf16(z * se)
        int e = i * 8, r = e / 640, c = e - r * 640;
        short8 v = *(const short8*)(zsrc + e);
        unsigned short o8[8];
        #pragma unroll
        for (int j = 0; j < 8; j++) {
            float f = bf2f(((const unsigned short*)&v)[j]) * seb[c + j];
            o8[j] = f2bf(f);
        }
        *(short8*)&sz[r * 648 + c] = *(short8*)o8;
    }
    __syncthreads();
    int wave = threadIdx.x >> 6, lane = threadIdx.x & 63, lid = lane & 15, quad = lane >> 4;
    const f32x4 z4 = {0.f, 0.f, 0.f, 0.f};
    int offG[5];
    #pragma unroll
    for (int i = 0; i < 5; i++) {
        int ct = wave + 8 * i;
        offG[i] = ((ct >> 2) * 80 + (ct & 3)) * 512 + lane * 8;
    }
    // ---- g-pass
    f32x4 ag[5][4];
    #pragma unroll
    for (int i = 0; i < 5; i++) { ag[i][0] = z4; ag[i][1] = z4; ag[i][2] = z4; ag[i][3] = z4; }
    short8 wbA[5], wbB[5];
    #pragma unroll
    for (int i = 0; i < 5; i++) wbA[i] = *(const short8*)(gwT + offG[i]);
    for (int kb = 0; kb < 20; kb += 2) {
        GLUSTEP(kb,     gwT, wbA, wbB, ag)
        GLUSTEP(kb + 1, gwT, wbB, wbA, ag)
    }
    // sigmoid(g + gb) in place (f32 -> no numeric change vs fused version)
    #pragma unroll
    for (int i = 0; i < 5; i++) {
        int col = (wave + 8 * i) * 16 + lid;
        float gbv = gb[col];
        #pragma unroll
        for (int rf = 0; rf < 4; rf++)
            #pragma unroll
            for (int r = 0; r < 4; r++)
                ag[i][rf][r] = 1.0f / (1.0f + __expf(-(ag[i][rf][r] + gbv)));
    }
    // ---- p-pass (reuses the same ping-pong buffers)
    f32x4 ap[5][4];
    #pragma unroll
    for (int i = 0; i < 5; i++) { ap[i][0] = z4; ap[i][1] = z4; ap[i][2] = z4; ap[i][3] = z4; }
    #pragma unroll
    for (int i = 0; i < 5; i++) wbA[i] = *(const short8*)(pwT + offG[i]);
    for (int kb = 0; kb < 20; kb += 2) {
        GLUSTEP(kb,     pwT, wbA, wbB, ap)
        GLUSTEP(kb + 1, pwT, wbB, wbA, ap)
    }
    // ---- h = sg*(p+pb) + (1-sg)*z_se  (into ag), block-local LN partial stats
    float hs[4][4] = {{0,0,0,0},{0,0,0,0},{0,0,0,0},{0,0,0,0}};
    float hq[4][4] = {{0,0,0,0},{0,0,0,0},{0,0,0,0},{0,0,0,0}};
    #pragma unroll
    for (int i = 0; i < 5; i++) {
        int ct = wave + 8 * i;
        int col = ct * 16 + lid;
        float pbv = pb[col];
        #pragma unroll
        for (int rf = 0; rf < 4; rf++) {
            #pragma unroll
            for (int r = 0; r < 4; r++) {
                int row = rf * 16 + quad * 4 + r;
                float sg = ag[i][rf][r];
                float pl = ap[i][rf][r] + pbv;
                float zv = bf2f(sz[row * 648 + col]);
                float hv = sg * pl + (1.0f - sg) * zv;
                ag[i][rf][r] = hv;                       // keep h in regs
                hs[rf][r] += hv; hq[rf][r] += hv * hv;
            }
        }
    }
    #pragma unroll
    for (int s = 1; s < 16; s <<= 1) {
        #pragma unroll
        for (int rf = 0; rf < 4; rf++)
            #pragma unroll
            for (int r = 0; r < 4; r++) {
                hs[rf][r] += __shfl_xor(hs[rf][r], s);
                hq[rf][r] += __shfl_xor(hq[rf][r], s);
            }
    }
    if (lid == 0) {
        #pragma unroll
        for (int rf = 0; rf < 4; rf++)
            #pragma unroll
            for (int r = 0; r < 4; r++) {
                int row = rf * 16 + quad * 4 + r;
                spart[row][wave] = hs[rf][r];
                sqart[row][wave] = hq[rf][r];
            }
    }
    __syncthreads();                                     // (A) all z reads + partials done
    if (threadIdx.x < 64) {
        float s1 = 0.f, s2 = 0.f;
        #pragma unroll
        for (int w = 0; w < 8; w++) { s1 += spart[threadIdx.x][w]; s2 += sqart[threadIdx.x][w]; }
        float mu = s1 * (1.0f / 640.0f);
        float var = s2 * (1.0f / 640.0f) - mu * mu;
        float rs = rsqrtf(var + EPSV);
        sA[threadIdx.x] = rs;
        sB[threadIdx.x] = -mu * rs;
    }
    __syncthreads();                                     // (B) stats ready
    // ---- write LN(h) in place over z_se
    #pragma unroll
    for (int i = 0; i < 5; i++) {
        int ct = wave + 8 * i;
        int col = ct * 16 + lid;
        float lw = ln_w[col], lb = ln_b[col];
        #pragma unroll
        for (int rf = 0; rf < 4; rf++) {
            #pragma unroll
            for (int r = 0; r < 4; r++) {
                int row = rf * 16 + quad * 4 + r;
                float f = ag[i][rf][r] * sA[row] + sB[row];
                sz[row * 648 + col] = f2bf(f * lw + lb);
            }
        }
    }
    __syncthreads();                                     // (C) h_ln staged
    // ---- out-proj GEMM
    int offO[4];
    #pragma unroll
    for (int i = 0; i < 4; i++) {
        int ct = wave + 8 * i;
        offO[i] = ((ct >> 2) * 80 + (ct & 3)) * 512 + lane * 8;
    }
    f32x4 acc[4][4];
    #pragma unroll
    for (int i = 0; i < 4; i++) { acc[i][0] = z4; acc[i][1] = z4; acc[i][2] = z4; acc[i][3] = z4; }
    short8 bA[4], bB[4];
    #pragma unroll
    for (int i = 0; i < 4; i++) bA[i] = *(const short8*)(owT + offO[i]);
    for (int kb = 0; kb < 20; kb += 2) {
        OSTEP(kb, bA, bB)
        OSTEP(kb + 1, bB, bA)
    }
    #pragma unroll
    for (int i = 0; i < 4; i++) {
        int ct = wave + 8 * i;
        int col = ct * 16 + lid;
        float obv = ob[col];
        float gs = 0.f, gq = 0.f;
        #pragma unroll
        for (int rf = 0; rf < 4; rf++) {
            #pragma unroll
            for (int r = 0; r < 4; r++) {
                int row = rf * 16 + quad * 4 + r;
                float v = acc[i][rf][r] + obv;
                outp[(size_t)(m0 + row) * 512 + col] = v;
                gs += v; gq += v * v;
            }
        }
        #pragma unroll
        for (int s = 1; s < 64; s <<= 1) { gs += __shfl_xor(gs, s); gq += __shfl_xor(gq, s); }
        if (lane == 0) {
            int grp = ct >> 2;
            atomicAdd(&gnstats[(bidx * 8 + grp) * 2 + 0], gs);
            atomicAdd(&gnstats[(bidx * 8 + grp) * 2 + 1], gq);
        }
    }
}

// ---------------------------------------------------------------- GroupNorm finalize (in-place on d_out)
__global__ void k_gn(float* __restrict__ outp, const float* __restrict__ gnstats,
                     const float* __restrict__ gn_w, const float* __restrict__ gn_b)
{
    int idx = blockIdx.x * 256 + threadIdx.x;
    size_t e = (size_t)idx * 4;
    int c = (int)(e & 511);
    size_t row = e >> 9;
    int b = (int)(row >> 11);
    int grp = c >> 6;
    float s1 = gnstats[(b * 8 + grp) * 2 + 0];
    float s2 = gnstats[(b * 8 + grp) * 2 + 1];
    const float inv = 1.0f / 131072.0f;
    float mu = s1 * inv;
    float var = s2 * inv - mu * mu;
    float rs = rsqrtf(var + EPSV);
    float4 v = *(const float4*)(outp + e);
    float4 w = *(const float4*)(gn_w + c);
    float4 bb = *(const float4*)(gn_b + c);
    float4 o;
    o.x = (v.x - mu) * rs * w.x + bb.x;
    o.y = (v.y - mu) * rs * w.y + bb.y;
    o.z = (v.z - mu) * rs * w.z + bb.z;
    o.w = (v.w - mu) * rs * w.w + bb.w;
    *(float4*)(outp + e) = o;
}

// ----------------------------------------------------------------
extern "C" void kernel_launch(void* const* d_in, const int* in_sizes, int n_in,
                              void* d_out, int out_size, void* d_ws, size_t ws_size,
                              hipStream_t stream)
{
    const float* x     = (const float*)d_in[0];
    const float* hw1   = (const float*)d_in[1];
    const float* hb1   = (const float*)d_in[2];
    const float* hw2   = (const float*)d_in[3];
    const float* hb2   = (const float*)d_in[4];
    const float* lw1   = (const float*)d_in[5];
    const float* lb1   = (const float*)d_in[6];
    const float* lw2   = (const float*)d_in[7];
    const float* lb2   = (const float*)d_in[8];
    const float* ew1   = (const float*)d_in[9];
    const float* eb1   = (const float*)d_in[10];
    const float* ew2   = (const float*)d_in[11];
    const float* eb2   = (const float*)d_in[12];
    const float* se_w1 = (const float*)d_in[13];
    const float* se_w2 = (const float*)d_in[14];
    const float* gw    = (const float*)d_in[15];
    const float* gb    = (const float*)d_in[16];
    const float* pw    = (const float*)d_in[17];
    const float* pb    = (const float*)d_in[18];
    const float* ln_w  = (const float*)d_in[19];
    const float* ln_b  = (const float*)d_in[20];
    const float* ow    = (const float*)d_in[21];
    const float* ob    = (const float*)d_in[22];
    const float* gn_w  = (const float*)d_in[23];
    const float* gn_b  = (const float*)d_in[24];

    char* ws = (char*)d_ws;
    size_t off = 0;
    unsigned short* w2T  = (unsigned short*)(ws + off); off += (size_t)640 * 256 * 2;
    float*          b2   = (float*)(ws + off);          off += 640 * 4;
    unsigned short* gwT  = (unsigned short*)(ws + off); off += (size_t)640 * 640 * 2;
    unsigned short* pwT  = (unsigned short*)(ws + off); off += (size_t)640 * 640 * 2;
    unsigned short* owT  = (unsigned short*)(ws + off); off += (size_t)512 * 640 * 2;
    unsigned short* w1T  = (unsigned short*)(ws + off); off += (size_t)640 * 32 * 2;
    float*          b1   = (float*)(ws + off);          off += 640 * 4;
    float*          ysum = (float*)(ws + off);          off += (size_t)64 * 640 * 4;
    float*          sebuf= (float*)(ws + off);          off += (size_t)64 * 640 * 4;
    float*          gnst = (float*)(ws + off);          off += (size_t)64 * 8 * 2 * 4;
    unsigned short* zbuf = (unsigned short*)(ws + off); off += (size_t)BT * 640 * 2;

    float* outp = (float*)d_out;

    hipMemsetAsync(ysum, 0, (size_t)64 * 640 * 4, stream);
    hipMemsetAsync(gnst, 0, (size_t)64 * 8 * 2 * 4, stream);

    kprep<<<512, 256, 0, stream>>>(hw1, lw1, ew1, hb1, lb1, eb1,
                                   hw2, lw2, ew2, hb2, lb2, eb2,
                                   gw, pw, ow, w1T, b1, w2T, b2, gwT, pwT, owT);
    k_z<<<BT / 64, 512, 0, stream>>>(x, w1T, b1, w2T, b2, zbuf, ysum);
    k_se<<<64, 256, 0, stream>>>(ysum, se_w1, se_w2, sebuf);
    k_gluout<<<BT / 64, 512, 0, stream>>>(zbuf, sebuf, gwT, pwT, gb, pb,
                                          ln_w, ln_b, owT, ob, outp, gnst);
    k_gn<<<(BT * 512) / (256 * 4), 256, 0, stream>>>(outp, gnst, gn_w, gn_b);
}